// Round 9
// baseline (203.209 us; speedup 1.0000x reference)
//
#include <hip/hip_runtime.h>

#define BB 4
#define TT 32
#define DD 256
#define NN 1024

// ws layout (float indices)
#define XN_OFF   0                      // xn [B*T][N]
#define TN_OFF   131072                 // tn [B*T][N]  (tn[b][t] = tgt_neurons[b][t+1])
#define PB_OFF   262144                 // p  [B*T][2][N]
#define RB_OFF   524288                 // r  [B*T][N]
#define FLG_OFF  655360                 // flags [3 stages][4 b][16 wg][32] u32 (one 128B line per flag)
#define FLG_WORDS 6144                  // 3*4*16*32
#define WS_END   (FLG_OFF + FLG_WORDS)

// ---------------- kernel 1: xn = relu(LN(x @ E)), tn shifted; grid = 64 ----------------
__global__ __launch_bounds__(256) void precompute_kernel(
    const float* __restrict__ x_seq, const float* __restrict__ targets,
    const float* __restrict__ E, float* __restrict__ ws)
{
    __shared__ float xr[4][DD];
    __shared__ float redS[4][4], redSS[4][4];
    const int blk = blockIdx.x;        // 0..63
    const int bt0 = blk * 2, bt1 = bt0 + 1;
    const int tid = threadIdx.x;
    const int lane = tid & 63, w = tid >> 6;

    xr[0][tid] = x_seq[(size_t)bt0 * DD + tid];
    xr[1][tid] = x_seq[(size_t)bt1 * DD + tid];
    xr[2][tid] = targets[(size_t)bt0 * DD + tid];
    xr[3][tid] = targets[(size_t)bt1 * DD + tid];
    __syncthreads();

    const float4* E4 = (const float4*)E;
    float4 acc[4];
#pragma unroll
    for (int r = 0; r < 4; ++r) acc[r] = make_float4(0.f, 0.f, 0.f, 0.f);
#pragma unroll 4
    for (int k = 0; k < DD; ++k) {
        float4 e = E4[(size_t)k * (NN / 4) + tid];
#pragma unroll
        for (int r = 0; r < 4; ++r) {
            float xv = xr[r][k];
            acc[r].x += xv * e.x; acc[r].y += xv * e.y;
            acc[r].z += xv * e.z; acc[r].w += xv * e.w;
        }
    }
    float s[4], ss[4];
#pragma unroll
    for (int r = 0; r < 4; ++r) {
        s[r]  = acc[r].x + acc[r].y + acc[r].z + acc[r].w;
        ss[r] = acc[r].x*acc[r].x + acc[r].y*acc[r].y + acc[r].z*acc[r].z + acc[r].w*acc[r].w;
    }
#pragma unroll
    for (int d = 1; d < 64; d <<= 1) {
#pragma unroll
        for (int r = 0; r < 4; ++r) {
            s[r]  += __shfl_xor(s[r], d, 64);
            ss[r] += __shfl_xor(ss[r], d, 64);
        }
    }
    if (lane == 0) {
#pragma unroll
        for (int r = 0; r < 4; ++r) { redS[w][r] = s[r]; redSS[w][r] = ss[r]; }
    }
    __syncthreads();
#pragma unroll
    for (int r = 0; r < 4; ++r) {
        s[r]  = redS[0][r] + redS[1][r] + redS[2][r] + redS[3][r];
        ss[r] = redSS[0][r] + redSS[1][r] + redSS[2][r] + redSS[3][r];
    }
#pragma unroll
    for (int r = 0; r < 4; ++r) {
        const float mu  = s[r] * (1.0f / NN);
        const float var = ss[r] * (1.0f / NN) - mu * mu;
        const float inv = rsqrtf(var + 1e-5f);
        float4 o;
        o.x = fmaxf(0.f, (acc[r].x - mu) * inv);
        o.y = fmaxf(0.f, (acc[r].y - mu) * inv);
        o.z = fmaxf(0.f, (acc[r].z - mu) * inv);
        o.w = fmaxf(0.f, (acc[r].w - mu) * inv);
        const int bt = (r & 1) ? bt1 : bt0;
        float* dst = nullptr;
        if (r < 2) dst = ws + XN_OFF + (size_t)bt * NN;
        else if ((bt & 31) > 0) dst = ws + TN_OFF + (size_t)(bt - 1) * NN;
        if (dst) ((float4*)dst)[tid] = o;
    }
}

// ---------------- kernel 2: persistent pipeline, cross-batch software pipelining ----------------
// R8 analysis: period is a serial latency chain (poll -> gather exposed at batch start).
// This version: (1) WAVE-LOCAL polls (each wave reads the full vector itself, so no
// block-wide poll barrier); (2) next batch's poll + gather + v-loads issued at the END
// of the current batch (after j=3's store) — latency overlaps drain+release+deferred
// update; (3) per-step x loads hoisted above the matvec (issue-early/use-late).
__device__ __forceinline__ float ald(const float* p) {
    return __hip_atomic_load(p, __ATOMIC_RELAXED, __HIP_MEMORY_SCOPE_AGENT);
}
__device__ __forceinline__ void ast(float* p, float v) {
    __hip_atomic_store(p, v, __ATOMIC_RELAXED, __HIP_MEMORY_SCOPE_AGENT);
}
__device__ __forceinline__ unsigned aldu_rlx(const unsigned* p) {
    return __hip_atomic_load(p, __ATOMIC_RELAXED, __HIP_MEMORY_SCOPE_AGENT);
}

// wave-local poll: all 64 lanes read the 16 producer flags (lane&15), __all over wave.
// seen is a per-lane monotone cache; compiler fence stops gather hoisting above the poll.
#define WAVE_POLL(TGT) do {                                                   \
    const unsigned _tgt = (unsigned)(TGT);                                    \
    if (!__all(seen >= _tgt)) {                                               \
        const unsigned* _p = inflags + (size_t)(lane & 15) * 32;              \
        int _g = 0;                                                           \
        for (;;) {                                                            \
            unsigned _v = aldu_rlx(_p);                                       \
            if (_v > seen) seen = _v;                                         \
            if (__all(seen >= _tgt)) break;                                   \
            __builtin_amdgcn_s_sleep(1);                                      \
            if (++_g > (1 << 22)) break;  /* fail visibly, never hang */      \
        }                                                                     \
    }                                                                         \
    asm volatile("" ::: "memory");                                            \
} while (0)

__global__ __launch_bounds__(512, 1) void mega_kernel(
    const float* __restrict__ Dy, float* __restrict__ out, float* __restrict__ ws)
{
    __shared__ float sh[6144];   // out-stage only: r[1024][4] + partial[2048]
    const int blk = blockIdx.x;  // 0..223  (1 WG/CU)
    const int tid = threadIdx.x;

    float* pb     = ws + PB_OFF;
    float* rb     = ws + RB_OFF;
    unsigned* flg = (unsigned*)(ws + FLG_OFF);

    if (blk < 192) {
        // ---- chain stages 0,1,2 ----
        const int stage = blk >> 6;          // 0,1,2
        const int b     = (blk >> 4) & 3;
        const int wg    = blk & 15;
        const int lane  = tid & 63;
        const int w     = tid >> 6;
        const int colbase = wg * 64 + w * 8;   // wave owns cols colbase..+7
        const float* xn = ws + XN_OFF + (size_t)b * TT * NN;
        const float* tn = ws + TN_OFF + (size_t)b * TT * NN;
        unsigned* myflag = flg + ((size_t)(stage * 4 + b) * 16 + wg) * 32;
        const unsigned* inflags =
            (stage > 0) ? flg + ((size_t)((stage - 1) * 4 + b) * 16) * 32 : (const unsigned*)0;
        unsigned seen = 0;   // monotone cache of min producer flag seen by this lane
        const size_t soff = (stage == 1) ? 0 : (size_t)NN;

        // interleaved rows: lane owns rows {i*64 + lane} -> all gathers 256B-coalesced
        float G[16][8];
#pragma unroll
        for (int i = 0; i < 16; ++i)
#pragma unroll
            for (int c = 0; c < 8; ++c)
                G[i][c] = (i * 64 + lane == colbase + c) ? 0.01f : 0.0f;

        float v1a = 0.f, v1b = 0.f, v1c = 0.f, v1d = 0.f;
        float v2a = 0.f, v2b = 0.f, v2c = 0.f, v2d = 0.f;
        float inA[16], inB[16];

        // ---- prologue: poll + gather batch 0 (steady-state batches prefetch at prev j=3) ----
        {
            float* pbase0 = pb + (size_t)(b * TT) * 2 * NN;
            if (stage == 0) {
#pragma unroll
                for (int i = 0; i < 16; ++i) inA[i] = xn[i * 64 + lane];
            } else {
                WAVE_POLL(4);
                if (stage == 2) {
                    const int co8 = colbase + (lane & 7);
                    v1a = ald(pbase0 + (size_t)0 * NN + co8);
                    v1b = ald(pbase0 + (size_t)2 * NN + co8);
                    v1c = ald(pbase0 + (size_t)4 * NN + co8);
                    v1d = ald(pbase0 + (size_t)6 * NN + co8);
                    v2a = ald(pbase0 + (size_t)0 * NN + NN + co8);
                    v2b = ald(pbase0 + (size_t)2 * NN + NN + co8);
                    v2c = ald(pbase0 + (size_t)4 * NN + NN + co8);
                    v2d = ald(pbase0 + (size_t)6 * NN + NN + co8);
                }
#pragma unroll
                for (int i = 0; i < 16; ++i) inA[i] = ald(pbase0 + soff + i * 64 + lane);
            }
        }

#pragma unroll 1
        for (int t = 0; t < TT; t += 4) {
            const int bt = b * TT + t;
            float* pbase = pb + (size_t)bt * 2 * NN;   // p1(t+j) = pbase + (2j)*NN, p2 = +NN

            // ======== 4 steps; next batch's poll/gather issued at end of j=3 ========
#pragma unroll
            for (int j = 0; j < 4; ++j) {
                const int tj = t + j;
                const float (&inC)[16] = (j & 1) ? inB : inA;   // static under full unroll
                float (&inN)[16]       = (j & 1) ? inA : inB;

                // within-batch prefetch of step j+1 (hidden under this step's compute)
                if (j < 3) {
                    if (stage == 0) {
#pragma unroll
                        for (int i = 0; i < 16; ++i)
                            inN[i] = xn[(size_t)(tj + 1) * NN + i * 64 + lane];
                    } else {
#pragma unroll
                        for (int i = 0; i < 16; ++i)
                            inN[i] = ald(pbase + (size_t)(2 * (j + 1)) * NN + soff + i * 64 + lane);
                    }
                }

                // issue-early x load for this step's G-update (consumed after the store)
                float x[16];
                if (j < 3 && stage != 0) {
#pragma unroll
                    for (int k = 0; k < 16; ++k) x[k] = xn[(size_t)tj * NN + k * 64 + lane];
                }

                float acc[8] = {0.f,0.f,0.f,0.f,0.f,0.f,0.f,0.f};
#pragma unroll
                for (int i = 0; i < 16; ++i)
#pragma unroll
                    for (int c = 0; c < 8; ++c) acc[c] += inC[i] * G[i][c];

                // reduce-scatter: lane ends with full sum for col colbase + (lane&7)
                float t4[8];
#pragma unroll
                for (int c = 0; c < 8; ++c) t4[c] = __shfl_xor(acc[c], 4, 64);
                const bool k2 = (lane & 4) != 0;
                float s4[4];
#pragma unroll
                for (int k = 0; k < 4; ++k) s4[k] = k2 ? (acc[4+k] + t4[4+k]) : (acc[k] + t4[k]);
                float t2[4];
#pragma unroll
                for (int k = 0; k < 4; ++k) t2[k] = __shfl_xor(s4[k], 2, 64);
                const bool k1 = (lane & 2) != 0;
                float s2[2];
#pragma unroll
                for (int k = 0; k < 2; ++k) s2[k] = k1 ? (s4[2+k] + t2[2+k]) : (s4[k] + t2[k]);
                float t1[2];
#pragma unroll
                for (int k = 0; k < 2; ++k) t1[k] = __shfl_xor(s2[k], 1, 64);
                float v = (lane & 1) ? (s2[1] + t1[1]) : (s2[0] + t1[0]);
                v += __shfl_xor(v, 8, 64);
                v += __shfl_xor(v, 16, 64);
                v += __shfl_xor(v, 32, 64);

                if (stage == 0) {
                    if (lane < 8) ast(pbase + (size_t)(2 * j) * NN + colbase + lane, v);
                } else if (stage == 1) {
                    if (lane < 8) ast(pbase + (size_t)(2 * j) * NN + NN + colbase + lane, v);
                } else {
                    const float v1o = (j == 0) ? v1a : (j == 1) ? v1b : (j == 2) ? v1c : v1d;
                    const float v2o = (j == 0) ? v2a : (j == 1) ? v2b : (j == 2) ? v2c : v2d;
                    float r = fmaxf(v, fmaxf(v1o, v2o));
                    if (lane < 8) ast(rb + (size_t)(bt + j) * NN + colbase + lane, r);
                }

                // end of j=3: poll + prefetch NEXT batch (overlaps drain/release/deferred upd)
                if (j == 3 && t + 4 < TT) {
                    float* pnext = pbase + (size_t)8 * NN;   // (bt+4)*2*NN
                    if (stage == 0) {
#pragma unroll
                        for (int i = 0; i < 16; ++i)
                            inN[i] = xn[(size_t)(t + 4) * NN + i * 64 + lane];
                    } else {
                        WAVE_POLL(t + 8);
#pragma unroll
                        for (int i = 0; i < 16; ++i)
                            inN[i] = ald(pnext + soff + i * 64 + lane);
                        if (stage == 2) {   // v1d/v2d already consumed by this j=3 store
                            const int co8 = colbase + (lane & 7);
                            v1a = ald(pnext + (size_t)0 * NN + co8);
                            v1b = ald(pnext + (size_t)2 * NN + co8);
                            v1c = ald(pnext + (size_t)4 * NN + co8);
                            v1d = ald(pnext + (size_t)6 * NN + co8);
                            v2a = ald(pnext + (size_t)0 * NN + NN + co8);
                            v2b = ald(pnext + (size_t)2 * NN + NN + co8);
                            v2c = ald(pnext + (size_t)4 * NN + NN + co8);
                            v2d = ald(pnext + (size_t)6 * NN + NN + co8);
                        }
                    }
                }

                // inline G update for steps j=0..2 (j=3 deferred past the release)
                if (j < 3) {
                    const float4 ta = *(const float4*)(tn + (size_t)tj * NN + colbase);
                    const float4 tb = *(const float4*)(tn + (size_t)tj * NN + colbase + 4);
                    const float tv[8] = {0.5f*ta.x, 0.5f*ta.y, 0.5f*ta.z, 0.5f*ta.w,
                                         0.5f*tb.x, 0.5f*tb.y, 0.5f*tb.z, 0.5f*tb.w};
#pragma unroll
                    for (int c = 0; c < 8; ++c) {
                        // tv[c] wave-uniform; tn relu output -> ~50% exact zeros; operands >=0
                        if (__builtin_amdgcn_readfirstlane(__float_as_uint(tv[c])) != 0u) {
                            if (stage == 0) {
#pragma unroll
                                for (int i = 0; i < 16; ++i)
                                    G[i][c] = fmaxf(G[i][c], inC[i] * tv[c]);
                            } else {
#pragma unroll
                                for (int i = 0; i < 16; ++i)
                                    G[i][c] = fmaxf(G[i][c], x[i] * tv[c]);
                            }
                        }
                    }
                }
            }

            __syncthreads();   // one drain for all 4 steps' device-scope stores (+prefetches)
            if (tid == 0)      // one RELEASE per batch: publishes steps t..t+3
                __hip_atomic_store(myflag, (unsigned)(t + 4),
                                   __ATOMIC_RELEASE, __HIP_MEMORY_SCOPE_AGENT);

            // deferred G update for step t+3 — after the release, overlaps flag propagation
            if (t + 3 < TT - 1) {
                const int tj = t + 3;
                float x[16];
                if (stage == 0) {
#pragma unroll
                    for (int k = 0; k < 16; ++k) x[k] = inB[k];   // j=3 used inB
                } else {
#pragma unroll
                    for (int k = 0; k < 16; ++k) x[k] = xn[(size_t)tj * NN + k * 64 + lane];
                }
                const float4 ta = *(const float4*)(tn + (size_t)tj * NN + colbase);
                const float4 tb = *(const float4*)(tn + (size_t)tj * NN + colbase + 4);
                const float tv[8] = {0.5f*ta.x, 0.5f*ta.y, 0.5f*ta.z, 0.5f*ta.w,
                                     0.5f*tb.x, 0.5f*tb.y, 0.5f*tb.z, 0.5f*tb.w};
#pragma unroll
                for (int c = 0; c < 8; ++c) {
                    if (__builtin_amdgcn_readfirstlane(__float_as_uint(tv[c])) != 0u) {
#pragma unroll
                        for (int i = 0; i < 16; ++i)
                            G[i][c] = fmaxf(G[i][c], x[i] * tv[c]);
                    }
                }
            }
        }
    } else {
        // ---- out stage: y = relu(r @ Dy) for 4 consecutive steps, single Dy pass ----
        const int k   = blk - 192;        // 0..31
        const int b   = k >> 3;
        const int t0  = (k & 7) * 4;
        const int bt0 = b * TT + t0;
        // RELAXED poll of the 16 stage-2 flags (monotone batch counts; t0+4 is a batch boundary)
        if (tid < 64) {
            const unsigned* p = flg + ((size_t)(2 * 4 + b) * 16 + (tid & 15)) * 32;
            const unsigned tgt = (unsigned)(t0 + 4);
            int g = 0;
            for (;;) {
                unsigned v = aldu_rlx(p);
                if (__all(v >= tgt)) break;
                __builtin_amdgcn_s_sleep(1);
                if (++g > (1 << 22)) break;
            }
        }
        __syncthreads();
        asm volatile("" ::: "memory");
#pragma unroll
        for (int j = 0; j < 4; ++j) {
            const float* r = rb + (size_t)(bt0 + j) * NN;
            sh[tid * 4 + j]         = ald(r + tid);
            sh[(tid + 512) * 4 + j] = ald(r + tid + 512);
        }
        __syncthreads();
        const int d = tid & 255, h = tid >> 8;
        float acc[4] = {0.f, 0.f, 0.f, 0.f};
        const int n0 = h * 512;
#pragma unroll 8
        for (int n = n0; n < n0 + 512; ++n) {
            const float dv = Dy[(size_t)n * DD + d];
            const float4 rv = *(const float4*)&sh[n * 4];   // wave-uniform n -> LDS broadcast
            acc[0] += rv.x * dv; acc[1] += rv.y * dv;
            acc[2] += rv.z * dv; acc[3] += rv.w * dv;
        }
#pragma unroll
        for (int j = 0; j < 4; ++j) sh[4096 + (h * 4 + j) * 256 + d] = acc[j];
        __syncthreads();
        if (tid < 256) {
#pragma unroll
            for (int j = 0; j < 4; ++j)
                out[(size_t)(bt0 + j) * DD + tid] =
                    fmaxf(0.f, sh[4096 + j * 256 + tid] + sh[4096 + (4 + j) * 256 + tid]);
        }
    }
}

extern "C" void kernel_launch(void* const* d_in, const int* in_sizes, int n_in,
                              void* d_out, int out_size, void* d_ws, size_t ws_size,
                              hipStream_t stream) {
    const float* x_seq   = (const float*)d_in[0];
    const float* targets = (const float*)d_in[1];
    const float* E       = (const float*)d_in[2];
    const float* Dy      = (const float*)d_in[3];
    float* out = (float*)d_out;
    float* ws  = (float*)d_ws;

    // zero the flags (data is flag-protected; flags are monotone batch counts)
    hipMemsetAsync(ws + FLG_OFF, 0, (size_t)FLG_WORDS * sizeof(unsigned), stream);

    precompute_kernel<<<BB * TT / 2, 256, 0, stream>>>(x_seq, targets, E, ws);
    mega_kernel<<<224, 512, 0, stream>>>(Dy, out, ws);
}

// Round 12
// 200.137 us; speedup vs baseline: 1.0153x; 1.0153x over previous
//
#include <hip/hip_runtime.h>

#define BB 4
#define TT 32
#define DD 256
#define NN 1024

// ws layout (float indices)
#define XN_OFF   0                      // xn [B*T][N]
#define TN_OFF   131072                 // tn [B*T][N]  (tn[b][t] = tgt_neurons[b][t+1])
#define PB_OFF   262144                 // p  [B*T][2][N]
#define RB_OFF   524288                 // r  [B*T][N]
#define FLG_OFF  655360                 // flags [3 stages][4 b][16 wg][32] u32 (one 128B line per flag)
#define FLG_WORDS 6144                  // 3*4*16*32
#define WS_END   (FLG_OFF + FLG_WORDS)

// ---------------- kernel 1: xn = relu(LN(x @ E)), tn shifted; grid = 64 ----------------
__global__ __launch_bounds__(256) void precompute_kernel(
    const float* __restrict__ x_seq, const float* __restrict__ targets,
    const float* __restrict__ E, float* __restrict__ ws)
{
    __shared__ float xr[4][DD];
    __shared__ float redS[4][4], redSS[4][4];
    const int blk = blockIdx.x;        // 0..63
    const int bt0 = blk * 2, bt1 = bt0 + 1;
    const int tid = threadIdx.x;
    const int lane = tid & 63, w = tid >> 6;

    xr[0][tid] = x_seq[(size_t)bt0 * DD + tid];
    xr[1][tid] = x_seq[(size_t)bt1 * DD + tid];
    xr[2][tid] = targets[(size_t)bt0 * DD + tid];
    xr[3][tid] = targets[(size_t)bt1 * DD + tid];
    __syncthreads();

    const float4* E4 = (const float4*)E;
    float4 acc[4];
#pragma unroll
    for (int r = 0; r < 4; ++r) acc[r] = make_float4(0.f, 0.f, 0.f, 0.f);
#pragma unroll 4
    for (int k = 0; k < DD; ++k) {
        float4 e = E4[(size_t)k * (NN / 4) + tid];
#pragma unroll
        for (int r = 0; r < 4; ++r) {
            float xv = xr[r][k];
            acc[r].x += xv * e.x; acc[r].y += xv * e.y;
            acc[r].z += xv * e.z; acc[r].w += xv * e.w;
        }
    }
    float s[4], ss[4];
#pragma unroll
    for (int r = 0; r < 4; ++r) {
        s[r]  = acc[r].x + acc[r].y + acc[r].z + acc[r].w;
        ss[r] = acc[r].x*acc[r].x + acc[r].y*acc[r].y + acc[r].z*acc[r].z + acc[r].w*acc[r].w;
    }
#pragma unroll
    for (int d = 1; d < 64; d <<= 1) {
#pragma unroll
        for (int r = 0; r < 4; ++r) {
            s[r]  += __shfl_xor(s[r], d, 64);
            ss[r] += __shfl_xor(ss[r], d, 64);
        }
    }
    if (lane == 0) {
#pragma unroll
        for (int r = 0; r < 4; ++r) { redS[w][r] = s[r]; redSS[w][r] = ss[r]; }
    }
    __syncthreads();
#pragma unroll
    for (int r = 0; r < 4; ++r) {
        s[r]  = redS[0][r] + redS[1][r] + redS[2][r] + redS[3][r];
        ss[r] = redSS[0][r] + redSS[1][r] + redSS[2][r] + redSS[3][r];
    }
#pragma unroll
    for (int r = 0; r < 4; ++r) {
        const float mu  = s[r] * (1.0f / NN);
        const float var = ss[r] * (1.0f / NN) - mu * mu;
        const float inv = rsqrtf(var + 1e-5f);
        float4 o;
        o.x = fmaxf(0.f, (acc[r].x - mu) * inv);
        o.y = fmaxf(0.f, (acc[r].y - mu) * inv);
        o.z = fmaxf(0.f, (acc[r].z - mu) * inv);
        o.w = fmaxf(0.f, (acc[r].w - mu) * inv);
        const int bt = (r & 1) ? bt1 : bt0;
        float* dst = nullptr;
        if (r < 2) dst = ws + XN_OFF + (size_t)bt * NN;
        else if ((bt & 31) > 0) dst = ws + TN_OFF + (size_t)(bt - 1) * NN;
        if (dst) ((float4*)dst)[tid] = o;
    }
}

// ---------------- kernel 2: persistent pipeline, 4-step batches, LDS-free chain ----------------
// Verified-good R8 structure: block-wide wave-0 poll + __syncthreads before any consumer
// data read (the per-wave-poll variants raced on replay). Direct per-lane gathers
// (interleaved rows i*64+lane, coalesced), within-batch 1-step prefetch, wave-uniform
// zero-skip on the G-update, one RELEASE per WG per 4-step batch.
__device__ __forceinline__ float ald(const float* p) {
    return __hip_atomic_load(p, __ATOMIC_RELAXED, __HIP_MEMORY_SCOPE_AGENT);
}
__device__ __forceinline__ void ast(float* p, float v) {
    __hip_atomic_store(p, v, __ATOMIC_RELAXED, __HIP_MEMORY_SCOPE_AGENT);
}
__device__ __forceinline__ unsigned aldu_rlx(const unsigned* p) {
    return __hip_atomic_load(p, __ATOMIC_RELAXED, __HIP_MEMORY_SCOPE_AGENT);
}

__global__ __launch_bounds__(512, 1) void mega_kernel(
    const float* __restrict__ Dy, float* __restrict__ out, float* __restrict__ ws)
{
    __shared__ float sh[6144];   // out-stage only: r[1024][4] + partial[2048]
    const int blk = blockIdx.x;  // 0..223  (1 WG/CU)
    const int tid = threadIdx.x;

    float* pb     = ws + PB_OFF;
    float* rb     = ws + RB_OFF;
    unsigned* flg = (unsigned*)(ws + FLG_OFF);

    if (blk < 192) {
        // ---- chain stages 0,1,2 ----
        const int stage = blk >> 6;          // 0,1,2
        const int b     = (blk >> 4) & 3;
        const int wg    = blk & 15;
        const int lane  = tid & 63;
        const int w     = tid >> 6;
        const int colbase = wg * 64 + w * 8;   // wave owns cols colbase..+7
        const float* xn = ws + XN_OFF + (size_t)b * TT * NN;
        const float* tn = ws + TN_OFF + (size_t)b * TT * NN;
        unsigned* myflag = flg + ((size_t)(stage * 4 + b) * 16 + wg) * 32;
        const unsigned* inflags =
            (stage > 0) ? flg + ((size_t)((stage - 1) * 4 + b) * 16) * 32 : (const unsigned*)0;
        unsigned seen = 0;   // monotone cache of min producer flag seen by this lane

        // interleaved rows: lane owns rows {i*64 + lane} -> all gathers 256B-coalesced
        float G[16][8];
#pragma unroll
        for (int i = 0; i < 16; ++i)
#pragma unroll
            for (int c = 0; c < 8; ++c)
                G[i][c] = (i * 64 + lane == colbase + c) ? 0.01f : 0.0f;

#pragma unroll 1
        for (int t = 0; t < TT; t += 4) {
            const int bt = b * TT + t;
            float* pbase = pb + (size_t)bt * 2 * NN;   // p1(t+j) = pbase + (2j)*NN, p2 = +NN

            float v1a = 0.f, v1b = 0.f, v1c = 0.f, v1d = 0.f;
            float v2a = 0.f, v2b = 0.f, v2c = 0.f, v2d = 0.f;

            if (stage != 0) {
                // one RELAXED poll covers all 4 steps: all producers at flag >= t+4
                const unsigned tgt = (unsigned)(t + 4);
                if (tid < 64) {
                    if (seen < tgt) {
                        const unsigned* p = inflags + (size_t)(tid & 15) * 32;
                        int g = 0;
                        for (;;) {
                            unsigned v = aldu_rlx(p);
                            if (v > seen) seen = v;
                            if (__all(seen >= tgt)) break;
                            __builtin_amdgcn_s_sleep(1);
                            if (++g > (1 << 22)) break;  // fail visibly, never hang
                        }
                    }
                }
                __syncthreads();
                asm volatile("" ::: "memory");   // no hoisting of data reads above the poll
                if (stage == 2) {   // 8 own-column loads, one latency window
                    const int co8 = colbase + (lane & 7);
                    v1a = ald(pbase + (size_t)0 * NN + co8);
                    v1b = ald(pbase + (size_t)2 * NN + co8);
                    v1c = ald(pbase + (size_t)4 * NN + co8);
                    v1d = ald(pbase + (size_t)6 * NN + co8);
                    v2a = ald(pbase + (size_t)0 * NN + NN + co8);
                    v2b = ald(pbase + (size_t)2 * NN + NN + co8);
                    v2c = ald(pbase + (size_t)4 * NN + NN + co8);
                    v2d = ald(pbase + (size_t)6 * NN + NN + co8);
                }
            }

            // prologue gather: step t+0 into inA (coalesced 256B per load)
            const size_t soff = (stage == 1) ? 0 : (size_t)NN;
            float inA[16], inB[16];
            if (stage == 0) {
#pragma unroll
                for (int i = 0; i < 16; ++i) inA[i] = xn[(size_t)t * NN + i * 64 + lane];
            } else {
#pragma unroll
                for (int i = 0; i < 16; ++i) inA[i] = ald(pbase + soff + i * 64 + lane);
            }

            // ======== 4 steps: prefetch(j+1) || matvec(j) -> store -> update ========
#pragma unroll
            for (int j = 0; j < 4; ++j) {
                const int tj = t + j;
                const float (&inC)[16] = (j & 1) ? inB : inA;   // static under full unroll
                float (&inN)[16]       = (j & 1) ? inA : inB;
                if (j < 3) {   // software-prefetch next step's vector; hidden by this step
                    if (stage == 0) {
#pragma unroll
                        for (int i = 0; i < 16; ++i)
                            inN[i] = xn[(size_t)(tj + 1) * NN + i * 64 + lane];
                    } else {
#pragma unroll
                        for (int i = 0; i < 16; ++i)
                            inN[i] = ald(pbase + (size_t)(2 * (j + 1)) * NN + soff + i * 64 + lane);
                    }
                }

                float acc[8] = {0.f,0.f,0.f,0.f,0.f,0.f,0.f,0.f};
#pragma unroll
                for (int i = 0; i < 16; ++i)
#pragma unroll
                    for (int c = 0; c < 8; ++c) acc[c] += inC[i] * G[i][c];

                // reduce-scatter: lane ends with full sum for col colbase + (lane&7)
                float t4[8];
#pragma unroll
                for (int c = 0; c < 8; ++c) t4[c] = __shfl_xor(acc[c], 4, 64);
                const bool k2 = (lane & 4) != 0;
                float s4[4];
#pragma unroll
                for (int k = 0; k < 4; ++k) s4[k] = k2 ? (acc[4+k] + t4[4+k]) : (acc[k] + t4[k]);
                float t2[4];
#pragma unroll
                for (int k = 0; k < 4; ++k) t2[k] = __shfl_xor(s4[k], 2, 64);
                const bool k1 = (lane & 2) != 0;
                float s2[2];
#pragma unroll
                for (int k = 0; k < 2; ++k) s2[k] = k1 ? (s4[2+k] + t2[2+k]) : (s4[k] + t2[k]);
                float t1[2];
#pragma unroll
                for (int k = 0; k < 2; ++k) t1[k] = __shfl_xor(s2[k], 1, 64);
                float v = (lane & 1) ? (s2[1] + t1[1]) : (s2[0] + t1[0]);
                v += __shfl_xor(v, 8, 64);
                v += __shfl_xor(v, 16, 64);
                v += __shfl_xor(v, 32, 64);

                if (stage == 0) {
                    if (lane < 8) ast(pbase + (size_t)(2 * j) * NN + colbase + lane, v);
                } else if (stage == 1) {
                    if (lane < 8) ast(pbase + (size_t)(2 * j) * NN + NN + colbase + lane, v);
                } else {
                    const float v1o = (j == 0) ? v1a : (j == 1) ? v1b : (j == 2) ? v1c : v1d;
                    const float v2o = (j == 0) ? v2a : (j == 1) ? v2b : (j == 2) ? v2c : v2d;
                    float r = fmaxf(v, fmaxf(v1o, v2o));
                    if (lane < 8) ast(rb + (size_t)(bt + j) * NN + colbase + lane, r);
                }

                // inline G update for steps j=0..2 (j=3 deferred past the release)
                if (j < 3) {
                    float x[16];
                    if (stage == 0) {
#pragma unroll
                        for (int k = 0; k < 16; ++k) x[k] = inC[k];
                    } else {
#pragma unroll
                        for (int k = 0; k < 16; ++k) x[k] = xn[(size_t)tj * NN + k * 64 + lane];
                    }
                    const float4 ta = *(const float4*)(tn + (size_t)tj * NN + colbase);
                    const float4 tb = *(const float4*)(tn + (size_t)tj * NN + colbase + 4);
                    const float tv[8] = {0.5f*ta.x, 0.5f*ta.y, 0.5f*ta.z, 0.5f*ta.w,
                                         0.5f*tb.x, 0.5f*tb.y, 0.5f*tb.z, 0.5f*tb.w};
#pragma unroll
                    for (int c = 0; c < 8; ++c) {
                        // tv[c] is wave-uniform (colbase has no lane term); tn is relu output
                        // -> ~50% exact zeros; x>=0, G>=0 so fmax(G, x*0)==G. Scalar skip:
                        if (__builtin_amdgcn_readfirstlane(__float_as_uint(tv[c])) != 0u) {
#pragma unroll
                            for (int i = 0; i < 16; ++i)
                                G[i][c] = fmaxf(G[i][c], x[i] * tv[c]);
                        }
                    }
                }
            }

            __syncthreads();   // one drain for all 4 steps' device-scope stores
            if (tid == 0)      // one RELEASE per batch: publishes steps t..t+3
                __hip_atomic_store(myflag, (unsigned)(t + 4),
                                   __ATOMIC_RELEASE, __HIP_MEMORY_SCOPE_AGENT);

            // deferred G update for step t+3 — after the release, overlaps flag propagation
            if (t + 3 < TT - 1) {
                const int tj = t + 3;
                float x[16];
                if (stage == 0) {
#pragma unroll
                    for (int k = 0; k < 16; ++k) x[k] = inB[k];   // j=3 used inB
                } else {
#pragma unroll
                    for (int k = 0; k < 16; ++k) x[k] = xn[(size_t)tj * NN + k * 64 + lane];
                }
                const float4 ta = *(const float4*)(tn + (size_t)tj * NN + colbase);
                const float4 tb = *(const float4*)(tn + (size_t)tj * NN + colbase + 4);
                const float tv[8] = {0.5f*ta.x, 0.5f*ta.y, 0.5f*ta.z, 0.5f*ta.w,
                                     0.5f*tb.x, 0.5f*tb.y, 0.5f*tb.z, 0.5f*tb.w};
#pragma unroll
                for (int c = 0; c < 8; ++c) {
                    if (__builtin_amdgcn_readfirstlane(__float_as_uint(tv[c])) != 0u) {
#pragma unroll
                        for (int i = 0; i < 16; ++i)
                            G[i][c] = fmaxf(G[i][c], x[i] * tv[c]);
                    }
                }
            }
        }
    } else {
        // ---- out stage: y = relu(r @ Dy) for 4 consecutive steps, single Dy pass ----
        const int k   = blk - 192;        // 0..31
        const int b   = k >> 3;
        const int t0  = (k & 7) * 4;
        const int bt0 = b * TT + t0;
        // RELAXED poll of the 16 stage-2 flags (monotone batch counts; t0+4 is a batch boundary)
        if (tid < 64) {
            const unsigned* p = flg + ((size_t)(2 * 4 + b) * 16 + (tid & 15)) * 32;
            const unsigned tgt = (unsigned)(t0 + 4);
            int g = 0;
            for (;;) {
                unsigned v = aldu_rlx(p);
                if (__all(v >= tgt)) break;
                __builtin_amdgcn_s_sleep(1);
                if (++g > (1 << 22)) break;
            }
        }
        __syncthreads();
        asm volatile("" ::: "memory");
#pragma unroll
        for (int j = 0; j < 4; ++j) {
            const float* r = rb + (size_t)(bt0 + j) * NN;
            sh[tid * 4 + j]         = ald(r + tid);
            sh[(tid + 512) * 4 + j] = ald(r + tid + 512);
        }
        __syncthreads();
        const int d = tid & 255, h = tid >> 8;
        float acc[4] = {0.f, 0.f, 0.f, 0.f};
        const int n0 = h * 512;
#pragma unroll 8
        for (int n = n0; n < n0 + 512; ++n) {
            const float dv = Dy[(size_t)n * DD + d];
            const float4 rv = *(const float4*)&sh[n * 4];   // wave-uniform n -> LDS broadcast
            acc[0] += rv.x * dv; acc[1] += rv.y * dv;
            acc[2] += rv.z * dv; acc[3] += rv.w * dv;
        }
#pragma unroll
        for (int j = 0; j < 4; ++j) sh[4096 + (h * 4 + j) * 256 + d] = acc[j];
        __syncthreads();
        if (tid < 256) {
#pragma unroll
            for (int j = 0; j < 4; ++j)
                out[(size_t)(bt0 + j) * DD + tid] =
                    fmaxf(0.f, sh[4096 + j * 256 + tid] + sh[4096 + (4 + j) * 256 + tid]);
        }
    }
}

extern "C" void kernel_launch(void* const* d_in, const int* in_sizes, int n_in,
                              void* d_out, int out_size, void* d_ws, size_t ws_size,
                              hipStream_t stream) {
    const float* x_seq   = (const float*)d_in[0];
    const float* targets = (const float*)d_in[1];
    const float* E       = (const float*)d_in[2];
    const float* Dy      = (const float*)d_in[3];
    float* out = (float*)d_out;
    float* ws  = (float*)d_ws;

    // zero the flags (data is flag-protected; flags are monotone batch counts)
    hipMemsetAsync(ws + FLG_OFF, 0, (size_t)FLG_WORDS * sizeof(unsigned), stream);

    precompute_kernel<<<BB * TT / 2, 256, 0, stream>>>(x_seq, targets, E, ws);
    mega_kernel<<<224, 512, 0, stream>>>(Dy, out, ws);
}